// Round 12
// baseline (106.811 us; speedup 1.0000x reference)
//
#include <hip/hip_runtime.h>
#include <math.h>

#define DD 4096
#define EE 64
#define NTOK 8192
#define BM 64            // tokens per block (4 waves x 16-token m-tiles)
#define KC 32            // K-chunk (one K=32 MFMA step)
#define NMB (NTOK / BM)  // 128 m-blocks
#define TAU 4e-3f        // near-tie flag threshold (3-term err ~1e-5 RMS)

typedef __attribute__((ext_vector_type(8))) short short8;
typedef __attribute__((ext_vector_type(4))) float f32x4;

__device__ __forceinline__ unsigned short f2bf(float f) {   // RNE bf16
    unsigned int u = __float_as_uint(f);
    return (unsigned short)((u + 0x7FFFu + ((u >> 16) & 1u)) >> 16);
}
__device__ __forceinline__ float bf2f(unsigned short h) {
    return __uint_as_float((unsigned int)h << 16);
}

// ---------------------------------------------------------------------------
// prep: W -> bf16 hi/lo split (Wh, Wl); zero the flag counter.
// ---------------------------------------------------------------------------
__global__ void moirai_prep(const float* __restrict__ W,
                            unsigned short* __restrict__ Wh,
                            unsigned short* __restrict__ Wl,
                            int* __restrict__ count) {
    int i = blockIdx.x * 256 + threadIdx.x;
    if (i == 0) *count = 0;
    if (i < EE * DD) {
        float w = W[i];
        unsigned short h = f2bf(w);
        Wh[i] = h;
        Wl[i] = f2bf(w - bf2f(h));
    }
}

// ---------------------------------------------------------------------------
// gemm: 3-term split-bf16 MFMA, NO LDS, NO barriers. Block = 4 waves; wave
// wv owns m-tile (tokens m0+wv*16..+15, disjoint -> no x sharing needed).
// Per chunk per lane: 32B x (direct per-lane fragment load, rows 16KB apart,
// 128B/row contiguous per wave) + 4x16B Wh + 4x16B Wl (L2-hot) -> in-reg
// hi/lo cvt -> 12 MFMAs. Register double-buffer (Pipe A/B), 1 chunk ahead.
// Partials -> part[ks][token][e].
// ---------------------------------------------------------------------------
struct Pipe {
    float4 x0, x1;
    short8 wh[4], wl[4];
};

__global__ __launch_bounds__(256, 3) void moirai_gemm(
        const float* __restrict__ x,
        const unsigned short* __restrict__ Wh,
        const unsigned short* __restrict__ Wl,
        float* __restrict__ part, int kslen) {
    const int t    = threadIdx.x;
    const int lane = t & 63;
    const int wv   = t >> 6;             // wave = m-tile 0..3
    const int mblk = blockIdx.x & (NMB - 1);
    const int ks   = blockIdx.x >> 7;    // grid = NMB * KS
    const int m0   = mblk * BM;
    const int k0   = ks * kslen;

    const int fr = lane & 15;            // fragment row (token / expert)
    const int fg = lane >> 4;            // k-group (8 elems)

    // per-lane fragment bases
    const float*          xb  = x  + (size_t)(m0 + wv * 16 + fr) * DD + k0 + fg * 8;
    const unsigned short* whb = Wh + (size_t)fr * DD + k0 + fg * 8;
    const unsigned short* wlb = Wl + (size_t)fr * DD + k0 + fg * 8;

    f32x4 aHH[4], aHL[4], aLH[4];
#pragma unroll
    for (int nt = 0; nt < 4; nt++) {
        aHH[nt] = f32x4{0.f, 0.f, 0.f, 0.f};
        aHL[nt] = f32x4{0.f, 0.f, 0.f, 0.f};
        aLH[nt] = f32x4{0.f, 0.f, 0.f, 0.f};
    }

    auto ld = [&](int c, Pipe& P) {
        P.x0 = *(const float4*)(xb + c * KC);
        P.x1 = *(const float4*)(xb + c * KC + 4);
#pragma unroll
        for (int nt = 0; nt < 4; nt++) {
            P.wh[nt] = *(const short8*)(whb + (size_t)nt * 16 * DD + c * KC);
            P.wl[nt] = *(const short8*)(wlb + (size_t)nt * 16 * DD + c * KC);
        }
    };
    auto compute = [&](const Pipe& P) {
        const float v[8] = {P.x0.x, P.x0.y, P.x0.z, P.x0.w,
                            P.x1.x, P.x1.y, P.x1.z, P.x1.w};
        short8 ah, al;
#pragma unroll
        for (int i = 0; i < 8; i++) {
            unsigned short hh = f2bf(v[i]);
            ah[i] = (short)hh;
            al[i] = (short)f2bf(v[i] - bf2f(hh));
        }
#pragma unroll
        for (int nt = 0; nt < 4; nt++) {
            aHH[nt] = __builtin_amdgcn_mfma_f32_16x16x32_bf16(ah, P.wh[nt], aHH[nt], 0, 0, 0);
            aHL[nt] = __builtin_amdgcn_mfma_f32_16x16x32_bf16(ah, P.wl[nt], aHL[nt], 0, 0, 0);
            aLH[nt] = __builtin_amdgcn_mfma_f32_16x16x32_bf16(al, P.wh[nt], aLH[nt], 0, 0, 0);
        }
    };

    const int nch = kslen / KC;          // 16 at KS=8 (even)
    Pipe A, B;
    ld(0, A);
    for (int c = 0; c < nch; c += 2) {
        if (c + 1 < nch) ld(c + 1, B);
        compute(A);
        if (c + 2 < nch) ld(c + 2, A);
        if (c + 1 < nch) compute(B);
    }

    // C/D (verified m89/m91): col = lane&15 -> expert, row = fg*4+j -> token
#pragma unroll
    for (int nt = 0; nt < 4; nt++) {
#pragma unroll
        for (int j = 0; j < 4; j++) {
            const int token = m0 + wv * 16 + fg * 4 + j;
            const float v = (aHH[nt][j] + aHL[nt][j]) + aLH[nt][j];
            part[((size_t)ks * NTOK + token) * EE + nt * 16 + fr] = v;
        }
    }
}

// ---------------------------------------------------------------------------
// topk pass 1: wave per token, lane = expert. f32 sum of KS partials + bias
// -> top-2 + third-max. Near-tie rows appended to flagged list (fix kernel
// overwrites them). Output: [gate_probs 16384 f32][indices-as-f32 16384].
// ---------------------------------------------------------------------------
__global__ void moirai_topk(const float* __restrict__ part,
                            const float* __restrict__ bias,
                            float* __restrict__ out,
                            int* __restrict__ count, int* __restrict__ list,
                            int KS) {
    const int lane  = threadIdx.x & 63;
    const int token = blockIdx.x * 4 + (threadIdx.x >> 6);

    float v = bias[lane];
    for (int ks = 0; ks < KS; ks++)
        v += part[((size_t)ks * NTOK + token) * EE + lane];

    // f32 top-2 butterfly with jax tie-break (lower index wins ties)
    float v1 = v, v2 = -3.4e38f;
    int   i1 = lane, i2 = 127;
#pragma unroll
    for (int off = 1; off < 64; off <<= 1) {
        float u1 = __shfl_xor(v1, off);
        float u2 = __shfl_xor(v2, off);
        int   j1 = __shfl_xor(i1, off);
        int   j2 = __shfl_xor(i2, off);
        bool u1_beats_v1 = (u1 > v1) || (u1 == v1 && j1 < i1);
        if (u1_beats_v1) {
            bool v1_beats_u2 = (v1 > u2) || (v1 == u2 && i1 < j2);
            if (v1_beats_u2) { v2 = v1; i2 = i1; }
            else             { v2 = u2; i2 = j2; }
            v1 = u1; i1 = j1;
        } else {
            bool u1_beats_v2 = (u1 > v2) || (u1 == v2 && j1 < i2);
            if (u1_beats_v2) { v2 = u1; i2 = j1; }
        }
    }

    // third-largest value (exclude top-2 by index)
    float ve = (lane == i1 || lane == i2) ? -3.4e38f : v;
#pragma unroll
    for (int off = 1; off < 64; off <<= 1)
        ve = fmaxf(ve, __shfl_xor(ve, off));

    if (lane == 0) {
        if ((v1 - v2 < TAU) || (v2 - ve < TAU)) {
            int pos = atomicAdd(count, 1);
            list[pos] = token;
        }
        double ex = exp((double)v2 - (double)v1);   // v1 >= v2 -> stable
        double s  = 1.0 + ex;
        out[token * 2 + 0] = (float)(1.0 / s);
        out[token * 2 + 1] = (float)(ex / s);
        out[NTOK * 2 + token * 2 + 0] = (float)i1;
        out[NTOK * 2 + token * 2 + 1] = (float)i2;
    }
}

// ---------------------------------------------------------------------------
// fix: exact f64 recompute of flagged rows, one block (1024 thr) per row.
// x row staged in LDS; 16 lanes per expert row -> coalesced 64B W reads.
// shfl-tree reduce (deterministic) -> wave 0 f64 top-2 (validated comparator).
// ---------------------------------------------------------------------------
__global__ __launch_bounds__(1024) void moirai_fix(
        const float* __restrict__ x, const float* __restrict__ W,
        const float* __restrict__ bias,
        const int* __restrict__ count, const int* __restrict__ list,
        float* __restrict__ out) {
    __shared__ float  xsr[DD];      // 16 KB
    __shared__ double red[EE];

    const int t = threadIdx.x;
    const int e = t >> 4;           // expert 0..63
    const int j = t & 15;           // k-strip within expert
    const int n = *count;

    for (int idx = blockIdx.x; idx < n; idx += gridDim.x) {
        const int token = list[idx];
        *(float4*)&xsr[t * 4] = *(const float4*)(x + (size_t)token * DD + t * 4);
        __syncthreads();

        const float* wr = W + (size_t)e * DD;
        double a0 = 0.0, a1 = 0.0, a2 = 0.0, a3 = 0.0;
#pragma unroll 8
        for (int i = 0; i < DD / 64; i++) {
            const int k = i * 64 + j * 4;
            const float4 xv = *(const float4*)&xsr[k];
            const float4 wv = *(const float4*)(wr + k);
            a0 += (double)xv.x * (double)wv.x;
            a1 += (double)xv.y * (double)wv.y;
            a2 += (double)xv.z * (double)wv.z;
            a3 += (double)xv.w * (double)wv.w;
        }
        double s = (a0 + a1) + (a2 + a3);
#pragma unroll
        for (int off = 1; off < 16; off <<= 1)
            s += __shfl_xor(s, off);          // within 16-lane group
        if (j == 0) red[e] = s;
        __syncthreads();

        if (t < 64) {                          // wave 0: f64 top-2
            double vd = red[t] + (double)bias[t];
            double e1 = vd, e2 = -1.0e300;
            int    f1 = t,  f2 = 127;
#pragma unroll
            for (int off = 1; off < 64; off <<= 1) {
                double u1 = __shfl_xor(e1, off);
                double u2 = __shfl_xor(e2, off);
                int    j1 = __shfl_xor(f1, off);
                int    j2 = __shfl_xor(f2, off);
                bool u1_beats_e1 = (u1 > e1) || (u1 == e1 && j1 < f1);
                if (u1_beats_e1) {
                    bool e1_beats_u2 = (e1 > u2) || (e1 == u2 && f1 < j2);
                    if (e1_beats_u2) { e2 = e1; f2 = f1; }
                    else             { e2 = u2; f2 = j2; }
                    e1 = u1; f1 = j1;
                } else {
                    bool u1_beats_e2 = (u1 > e2) || (u1 == e2 && j1 < f2);
                    if (u1_beats_e2) { e2 = u1; f2 = j1; }
                }
            }
            if (t == 0) {
                double ex = exp(e2 - e1);
                double sm = 1.0 + ex;
                out[token * 2 + 0] = (float)(1.0 / sm);
                out[token * 2 + 1] = (float)(ex / sm);
                out[NTOK * 2 + token * 2 + 0] = (float)f1;
                out[NTOK * 2 + token * 2 + 1] = (float)f2;
            }
        }
        __syncthreads();   // LDS reuse guard
    }
}

// ---------------------------------------------------------------------------
extern "C" void kernel_launch(void* const* d_in, const int* in_sizes, int n_in,
                              void* d_out, int out_size, void* d_ws, size_t ws_size,
                              hipStream_t stream) {
    const float* x = (const float*)d_in[0];
    const float* W = (const float*)d_in[1];
    const float* b = (const float*)d_in[2];
    float* out = (float*)d_out;

    // ws layout: [count|list : 64 KB][Wh 512 KB][Wl 512 KB][partials]
    const size_t HDR = 65536;
    const size_t WSZ = (size_t)EE * DD * 2;
    int*            count = (int*)d_ws;
    int*            list  = (int*)d_ws + 1;
    unsigned short* Wh    = (unsigned short*)((char*)d_ws + HDR);
    unsigned short* Wl    = (unsigned short*)((char*)d_ws + HDR + WSZ);
    float*          part  = (float*)((char*)d_ws + HDR + 2 * WSZ);

    int KS = 8;  // K-split; kslen stays a multiple of KC (and nch even)
    while (KS > 1 && HDR + 2 * WSZ + (size_t)KS * NTOK * EE * 4 > ws_size)
        KS >>= 1;
    const int kslen = DD / KS;

    moirai_prep<<<(EE * DD + 255) / 256, 256, 0, stream>>>(W, Wh, Wl, count);
    moirai_gemm<<<NMB * KS, 256, 0, stream>>>(x, Wh, Wl, part, kslen);
    moirai_topk<<<NTOK / 4, 256, 0, stream>>>(part, b, out, count, list, KS);
    moirai_fix<<<256, 1024, 0, stream>>>(x, W, b, count, list, out);
}

// Round 13
// 59.295 us; speedup vs baseline: 1.8013x; 1.8013x over previous
//
#include <hip/hip_runtime.h>
#include <math.h>

#define DD 4096
#define EE 64
#define NTOK 8192
#define BM 128           // tokens per block
#define KC 32            // K-chunk per pipeline step
#define NMB (NTOK / BM)  // 64 m-blocks
#define WSTR 40          // W LDS row stride in bf16 (80 B, 16B-aligned)
#define TAU 4e-3f        // near-tie flag threshold (split err ~1e-5 RMS)

typedef __attribute__((ext_vector_type(8))) short short8;
typedef __attribute__((ext_vector_type(4))) float f32x4;

__device__ __forceinline__ unsigned short f2bf(float f) {   // RNE bf16
    unsigned int u = __float_as_uint(f);
    return (unsigned short)((u + 0x7FFFu + ((u >> 16) & 1u)) >> 16);
}
__device__ __forceinline__ float bf2f(unsigned short h) {
    return __uint_as_float((unsigned int)h << 16);
}

// ---------------------------------------------------------------------------
// prep: W -> bf16 hi/lo split (Wh, Wl); zero the flag counter.
// ---------------------------------------------------------------------------
__global__ void moirai_prep(const float* __restrict__ W,
                            unsigned short* __restrict__ Wh,
                            unsigned short* __restrict__ Wl,
                            int* __restrict__ count) {
    int i = blockIdx.x * 256 + threadIdx.x;
    if (i == 0) *count = 0;
    if (i < EE * DD) {
        float w = W[i];
        unsigned short h = f2bf(w);
        Wh[i] = h;
        Wl[i] = f2bf(w - bf2f(h));
    }
}

// ---------------------------------------------------------------------------
// gemm (m97-lite): 3-term split-bf16 MFMA, merged-acc (HH | HL+LH).
// Block = 256 thr (4 waves) = 128 tok x 64 exp x K-slice. Wave wv: m-frags
// {2wv,2wv+1}, n-frags 0..3 -> 24 MFMA per K=32 step.
// x: global_load_lds dwordx4 x16/step, source-swizzled k' = k ^ 4*(r&7) ->
//    uniform-bank ds_read_b128 fragment reads; cvt f32->bf16 hi/lo at read.
// W: global->reg->ds_write once per step (padded stride-40 rows).
// ONE __syncthreads per step drains everything. Partials -> part[ks][tok][e].
// ---------------------------------------------------------------------------
__global__ __launch_bounds__(256, 2) void moirai_gemm(
        const float* __restrict__ x,
        const unsigned short* __restrict__ Wh,
        const unsigned short* __restrict__ Wl,
        float* __restrict__ part, int kslen) {
    __shared__ __align__(16) float          xs[2][BM * KC];     // 32 KB
    __shared__ __align__(16) unsigned short whs[2][EE * WSTR];  // 10 KB
    __shared__ __align__(16) unsigned short wls[2][EE * WSTR];  // 10 KB

    const int t    = threadIdx.x;
    const int lane = t & 63;
    const int wv   = t >> 6;             // wave 0..3
    const int mblk = blockIdx.x & (NMB - 1);
    const int ks   = blockIdx.x >> 6;    // grid = NMB * KS
    const int m0   = mblk * BM;
    const int k0   = ks * kslen;

    const int fr = lane & 15;            // fragment row (token / expert)
    const int fg = lane >> 4;            // k-group (8 elems)

    const int we  = t >> 2;              // W staging: row 0..63
    const int wsg = t & 3;               // 8-bf16 segment 0..3

    f32x4 accH[2][4], accL[2][4];
#pragma unroll
    for (int mf = 0; mf < 2; mf++)
#pragma unroll
        for (int nt = 0; nt < 4; nt++) {
            accH[mf][nt] = f32x4{0.f, 0.f, 0.f, 0.f};
            accL[mf][nt] = f32x4{0.f, 0.f, 0.f, 0.f};
        }

    // x staging: wave wv issues 4 global_load_lds (1 KB each, LDS-linear).
    // instr (wv,j), lane l -> LDS words (wv*4+j)*256 + l*4;
    // row r = wv*32 + j*8 + (l>>3); k = ((l&7)*4) ^ (4*(r&7)).
    auto stage_x = [&](int p, int c) {
        const int kb = k0 + c * KC;
#pragma unroll
        for (int j = 0; j < 4; j++) {
            const int r = wv * 32 + j * 8 + (lane >> 3);
            const int k = ((lane & 7) * 4) ^ (4 * (r & 7));
            const float* gp = x + (size_t)(m0 + r) * DD + kb + k;
            float* lp = &xs[p][(wv * 4 + j) * 256];   // wave-uniform base
            __builtin_amdgcn_global_load_lds(
                (const __attribute__((address_space(1))) void*)gp,
                (__attribute__((address_space(3))) void*)lp, 16, 0, 0);
        }
    };

    uint4 whr, wlr;
    auto ldW = [&](int c) {
        const int kb = k0 + c * KC;
        whr = *(const uint4*)(Wh + (size_t)we * DD + kb + wsg * 8);
        wlr = *(const uint4*)(Wl + (size_t)we * DD + kb + wsg * 8);
    };
    auto stW = [&](int p) {
        *(uint4*)&whs[p][we * WSTR + wsg * 8] = whr;
        *(uint4*)&wls[p][we * WSTR + wsg * 8] = wlr;
    };

    auto compute = [&](int p) {
        short8 ah[2], al[2], bh[4], bl[4];
#pragma unroll
        for (int mf = 0; mf < 2; mf++) {
            const int r = (wv * 2 + mf) * 16 + fr;
            const int q = 4 * (fr & 7);          // r&7 == fr&7
            const float4 a0 = *(const float4*)&xs[p][r * 32 + ((fg * 8) ^ q)];
            const float4 a1 = *(const float4*)&xs[p][r * 32 + ((fg * 8 + 4) ^ q)];
            const float v[8] = {a0.x, a0.y, a0.z, a0.w, a1.x, a1.y, a1.z, a1.w};
#pragma unroll
            for (int i = 0; i < 8; i++) {
                unsigned short hh = f2bf(v[i]);
                ah[mf][i] = (short)hh;
                al[mf][i] = (short)f2bf(v[i] - bf2f(hh));
            }
        }
#pragma unroll
        for (int nt = 0; nt < 4; nt++) {
            const int e = nt * 16 + fr;
            bh[nt] = *(const short8*)&whs[p][e * WSTR + fg * 8];
            bl[nt] = *(const short8*)&wls[p][e * WSTR + fg * 8];
        }
#pragma unroll
        for (int mf = 0; mf < 2; mf++)
#pragma unroll
            for (int nt = 0; nt < 4; nt++) {
                accH[mf][nt] = __builtin_amdgcn_mfma_f32_16x16x32_bf16(
                    ah[mf], bh[nt], accH[mf][nt], 0, 0, 0);
                accL[mf][nt] = __builtin_amdgcn_mfma_f32_16x16x32_bf16(
                    ah[mf], bl[nt], accL[mf][nt], 0, 0, 0);
                accL[mf][nt] = __builtin_amdgcn_mfma_f32_16x16x32_bf16(
                    al[mf], bh[nt], accL[mf][nt], 0, 0, 0);
            }
    };

    const int nch = kslen / KC;          // 16 at KS=8
    ldW(0);
    stage_x(0, 0);
    stW(0);
    __syncthreads();                     // buf 0 staged & visible

    for (int c = 0; c < nch; c++) {
        const int p = c & 1;
        if (c + 1 < nch) {
            stage_x(p ^ 1, c + 1);       // async DMA into other buffer
            ldW(c + 1);                  // W regs in flight under compute
        }
        compute(p);
        if (c + 1 < nch) stW(p ^ 1);     // vmcnt wait auto-inserted here
        __syncthreads();                 // drain + visibility, once per step
    }

    // C/D (verified m89/m91): col = lane&15 -> expert, row = fg*4+j -> token
#pragma unroll
    for (int mf = 0; mf < 2; mf++)
#pragma unroll
        for (int nt = 0; nt < 4; nt++)
#pragma unroll
            for (int j = 0; j < 4; j++) {
                const int token = m0 + (wv * 2 + mf) * 16 + fg * 4 + j;
                const float v = accH[mf][nt][j] + accL[mf][nt][j];
                part[((size_t)ks * NTOK + token) * EE + nt * 16 + fr] = v;
            }
}

// ---------------------------------------------------------------------------
// topk pass 1: wave per token, lane = expert. f32 sum of KS partials + bias
// -> top-2 + third-max. Near-tie rows appended to flagged list (fix kernel
// overwrites them). Output: [gate_probs 16384 f32][indices-as-f32 16384].
// ---------------------------------------------------------------------------
__global__ void moirai_topk(const float* __restrict__ part,
                            const float* __restrict__ bias,
                            float* __restrict__ out,
                            int* __restrict__ count, int* __restrict__ list,
                            int KS) {
    const int lane  = threadIdx.x & 63;
    const int token = blockIdx.x * 4 + (threadIdx.x >> 6);

    float v = bias[lane];
    for (int ks = 0; ks < KS; ks++)
        v += part[((size_t)ks * NTOK + token) * EE + lane];

    // f32 top-2 butterfly with jax tie-break (lower index wins ties)
    float v1 = v, v2 = -3.4e38f;
    int   i1 = lane, i2 = 127;
#pragma unroll
    for (int off = 1; off < 64; off <<= 1) {
        float u1 = __shfl_xor(v1, off);
        float u2 = __shfl_xor(v2, off);
        int   j1 = __shfl_xor(i1, off);
        int   j2 = __shfl_xor(i2, off);
        bool u1_beats_v1 = (u1 > v1) || (u1 == v1 && j1 < i1);
        if (u1_beats_v1) {
            bool v1_beats_u2 = (v1 > u2) || (v1 == u2 && i1 < j2);
            if (v1_beats_u2) { v2 = v1; i2 = i1; }
            else             { v2 = u2; i2 = j2; }
            v1 = u1; i1 = j1;
        } else {
            bool u1_beats_v2 = (u1 > v2) || (u1 == v2 && j1 < i2);
            if (u1_beats_v2) { v2 = u1; i2 = j1; }
        }
    }

    // third-largest value (exclude top-2 by index)
    float ve = (lane == i1 || lane == i2) ? -3.4e38f : v;
#pragma unroll
    for (int off = 1; off < 64; off <<= 1)
        ve = fmaxf(ve, __shfl_xor(ve, off));

    if (lane == 0) {
        if ((v1 - v2 < TAU) || (v2 - ve < TAU)) {
            int pos = atomicAdd(count, 1);
            list[pos] = token;
        }
        double ex = exp((double)v2 - (double)v1);   // v1 >= v2 -> stable
        double s  = 1.0 + ex;
        out[token * 2 + 0] = (float)(1.0 / s);
        out[token * 2 + 1] = (float)(ex / s);
        out[NTOK * 2 + token * 2 + 0] = (float)i1;
        out[NTOK * 2 + token * 2 + 1] = (float)i2;
    }
}

// ---------------------------------------------------------------------------
// fix: exact f64 recompute of flagged rows, one block (1024 thr) per row.
// x row staged in LDS; 16 lanes per expert row -> coalesced 64B W reads.
// shfl-tree reduce (deterministic) -> wave 0 f64 top-2 (validated comparator).
// ---------------------------------------------------------------------------
__global__ __launch_bounds__(1024) void moirai_fix(
        const float* __restrict__ x, const float* __restrict__ W,
        const float* __restrict__ bias,
        const int* __restrict__ count, const int* __restrict__ list,
        float* __restrict__ out) {
    __shared__ float  xsr[DD];      // 16 KB
    __shared__ double red[EE];

    const int t = threadIdx.x;
    const int e = t >> 4;           // expert 0..63
    const int j = t & 15;           // k-strip within expert
    const int n = *count;

    for (int idx = blockIdx.x; idx < n; idx += gridDim.x) {
        const int token = list[idx];
        *(float4*)&xsr[t * 4] = *(const float4*)(x + (size_t)token * DD + t * 4);
        __syncthreads();

        const float* wr = W + (size_t)e * DD;
        double a0 = 0.0, a1 = 0.0, a2 = 0.0, a3 = 0.0;
#pragma unroll 8
        for (int i = 0; i < DD / 64; i++) {
            const int k = i * 64 + j * 4;
            const float4 xv = *(const float4*)&xsr[k];
            const float4 wv = *(const float4*)(wr + k);
            a0 += (double)xv.x * (double)wv.x;
            a1 += (double)xv.y * (double)wv.y;
            a2 += (double)xv.z * (double)wv.z;
            a3 += (double)xv.w * (double)wv.w;
        }
        double s = (a0 + a1) + (a2 + a3);
#pragma unroll
        for (int off = 1; off < 16; off <<= 1)
            s += __shfl_xor(s, off);          // within 16-lane group
        if (j == 0) red[e] = s;
        __syncthreads();

        if (t < 64) {                          // wave 0: f64 top-2
            double vd = red[t] + (double)bias[t];
            double e1 = vd, e2 = -1.0e300;
            int    f1 = t,  f2 = 127;
#pragma unroll
            for (int off = 1; off < 64; off <<= 1) {
                double u1 = __shfl_xor(e1, off);
                double u2 = __shfl_xor(e2, off);
                int    j1 = __shfl_xor(f1, off);
                int    j2 = __shfl_xor(f2, off);
                bool u1_beats_e1 = (u1 > e1) || (u1 == e1 && j1 < f1);
                if (u1_beats_e1) {
                    bool e1_beats_u2 = (e1 > u2) || (e1 == u2 && f1 < j2);
                    if (e1_beats_u2) { e2 = e1; f2 = f1; }
                    else             { e2 = u2; f2 = j2; }
                    e1 = u1; f1 = j1;
                } else {
                    bool u1_beats_e2 = (u1 > e2) || (u1 == e2 && j1 < f2);
                    if (u1_beats_e2) { e2 = u1; f2 = j1; }
                }
            }
            if (t == 0) {
                double ex = exp(e2 - e1);
                double sm = 1.0 + ex;
                out[token * 2 + 0] = (float)(1.0 / sm);
                out[token * 2 + 1] = (float)(ex / sm);
                out[NTOK * 2 + token * 2 + 0] = (float)f1;
                out[NTOK * 2 + token * 2 + 1] = (float)f2;
            }
        }
        __syncthreads();   // LDS reuse guard
    }
}

// ---------------------------------------------------------------------------
extern "C" void kernel_launch(void* const* d_in, const int* in_sizes, int n_in,
                              void* d_out, int out_size, void* d_ws, size_t ws_size,
                              hipStream_t stream) {
    const float* x = (const float*)d_in[0];
    const float* W = (const float*)d_in[1];
    const float* b = (const float*)d_in[2];
    float* out = (float*)d_out;

    // ws layout: [count|list : 64 KB][Wh 512 KB][Wl 512 KB][partials]
    const size_t HDR = 65536;
    const size_t WSZ = (size_t)EE * DD * 2;
    int*            count = (int*)d_ws;
    int*            list  = (int*)d_ws + 1;
    unsigned short* Wh    = (unsigned short*)((char*)d_ws + HDR);
    unsigned short* Wl    = (unsigned short*)((char*)d_ws + HDR + WSZ);
    float*          part  = (float*)((char*)d_ws + HDR + 2 * WSZ);

    int KS = 8;  // K-split; kslen stays a multiple of KC
    while (KS > 1 && HDR + 2 * WSZ + (size_t)KS * NTOK * EE * 4 > ws_size)
        KS >>= 1;
    const int kslen = DD / KS;

    moirai_prep<<<(EE * DD + 255) / 256, 256, 0, stream>>>(W, Wh, Wl, count);
    moirai_gemm<<<NMB * KS, 256, 0, stream>>>(x, Wh, Wl, part, kslen);
    moirai_topk<<<NTOK / 4, 256, 0, stream>>>(part, b, out, count, list, KS);
    moirai_fix<<<256, 1024, 0, stream>>>(x, W, b, count, list, out);
}